// Round 18
// baseline (290.481 us; speedup 1.0000x reference)
//
#include <hip/hip_runtime.h>
#include <hip/hip_bf16.h>

// C3 partial connection via MFMA (fp16 in / fp32 acc), full-row-slab form.
// y = conv5x5(channel-subsets) + bias; out = 1.7159*tanh(2/3*y).
// M = 16 px, N = 16 oc, K = dx*8 + c (c pad 6->8); 2 mfma_16x16x32_f16 per
// (row, dy): m=0 dx0..3, m=1 dx4 (dx5..7 zero-weighted).
//
// R19 = R17 (best: 155us) + store-path fix ONLY:
//   - even output rows: one float4 nontemporal store per lane -> each 64B
//     sector filled by ONE instruction (was 8x 8B across 2 instrs -> 2
//     merge-requests/sector at L2). Odd rows are 8B-aligned by layout
//     (138 = 2 mod 4) and keep float2; last x-tile (x0t=122) keeps float2.
//   - nontemporal on all output stores (write-once stream; stop polluting
//     L2/L3 that should retain x + weight table).
// Retained: 12-row full-width slabs, LOAD-ALL/PACK-ALL staging, tiles-fastest
// store order, chunked XCD swizzle, setprio.

#define IH 142
#define IW 142
#define OH 138
#define OW 138
#define SROWS 16
#define PXP 148                 // padded px per staged row
#define ROW_H (PXP * 8)         // 1184 halfs per row
#define ROW_D (PXP * 4)         // 592 dwords per row
#define NSLAB 12
#define NWG (NSLAB * 256)       // 3072, divisible by 8
#define CPX (NWG / 8)           // 384

typedef _Float16 f16x8 __attribute__((ext_vector_type(8)));
typedef float f32x4 __attribute__((ext_vector_type(4)));
typedef float f32x2 __attribute__((ext_vector_type(2)));
typedef unsigned int u32x4 __attribute__((ext_vector_type(4)));

// WIDX[oc][c] = src*64 + block-index, or -1. src 0=w3(6,3,5,5) 1=w4(9,4,5,5)
// 2=w6(1,6,5,5); weight elem = blk*25 + dy*5 + dx.
__device__ __constant__ const short WIDX16[16][6] = {
  {   0,    1,    2,   -1,   -1,   -1},   // oc0  {0,1,2}
  {  -1,    3,    4,    5,   -1,   -1},   // oc1  {1,2,3}
  {  -1,   -1,    6,    7,    8,   -1},   // oc2  {2,3,4}
  {  -1,   -1,   -1,    9,   10,   11},   // oc3  {3,4,5}
  {  12,   -1,   -1,   -1,   13,   14},   // oc4  {0,4,5}
  {  15,   16,   -1,   -1,   -1,   17},   // oc5  {0,1,5}
  {64+0, 64+1, 64+2, 64+3,   -1,   -1},   // oc6  {0,1,2,3}
  {  -1, 64+4, 64+5, 64+6, 64+7,   -1},   // oc7  {1,2,3,4}
  {  -1,   -1, 64+8, 64+9, 64+10, 64+11}, // oc8  {2,3,4,5}
  {64+12,  -1,   -1, 64+13, 64+14, 64+15},// oc9  {0,3,4,5}
  {64+16, 64+17, -1,   -1, 64+18, 64+19}, // oc10 {0,1,4,5}
  {64+20, 64+21, 64+22, -1,  -1, 64+23},  // oc11 {0,1,2,5}
  {64+24, 64+25, -1, 64+26, 64+27,  -1},  // oc12 {0,1,3,4}
  {  -1, 64+28, 64+29, -1, 64+30, 64+31}, // oc13 {1,2,4,5}
  {64+32,  -1, 64+33, 64+34, -1, 64+35},  // oc14 {0,2,3,5}
  {128+0, 128+1, 128+2, 128+3, 128+4, 128+5}, // oc15 {0..5}
};

// prep: per-lane pre-swizzled B fragments, 5 dy x 2 m x 64 lanes x 8 halfs.
// k = m*32 + q*8 + j -> dx = k>>3, c = k&7; zero unless dx<5 && c<6 && consumed.
__global__ void wprep_kernel(const float* __restrict__ w3, const float* __restrict__ w4,
                             const float* __restrict__ w6, _Float16* __restrict__ tab) {
  int t = blockIdx.x * 256 + threadIdx.x;
  if (t >= 5120) return;
  int j = t & 7, lane = (t >> 3) & 63, dm = t >> 9;
  int dy = dm >> 1, m = dm & 1;
  int q = lane >> 4, oc = lane & 15;
  int k = m * 32 + q * 8 + j;
  int dx = k >> 3, c = k & 7;
  float v = 0.f;
  if (c < 6 && dx < 5) {
    int e = WIDX16[oc][c];
    if (e >= 0) {
      int src = e >> 6, blk = e & 63;
      const float* wp = (src == 0) ? w3 : (src == 1) ? w4 : w6;
      v = wp[blk * 25 + dy * 5 + dx];
    }
  }
  tab[t] = (_Float16)v;
}

__device__ __forceinline__ unsigned int pkh(float a, float b) {
  _Float16 ha = (_Float16)a, hb = (_Float16)b;
  unsigned short ua = __builtin_bit_cast(unsigned short, ha);
  unsigned short ub = __builtin_bit_cast(unsigned short, hb);
  return (unsigned int)ua | ((unsigned int)ub << 16);
}

__device__ __forceinline__ float act(float y) {
  const float TS = 1.9235933878519512f;  // 2*(2/3)*log2(e)
  const float e = __builtin_amdgcn_exp2f(y * TS);
  return fmaf(-2.f * 1.7159f, __builtin_amdgcn_rcpf(e + 1.f), 1.7159f);
}

// Block: 256 threads = 4 waves, owns rows y0..y0+11 x FULL width x 16 oc.
// Logical grid: (12 y-slabs, 256 images), XCD-chunk-swizzled.
__global__ __launch_bounds__(256, 4)
void c3_mfma(const float* __restrict__ x,
             const float* __restrict__ b3, const float* __restrict__ b4,
             const float* __restrict__ b6, const _Float16* __restrict__ tab,
             float* __restrict__ out) {
  __shared__ __attribute__((aligned(16))) _Float16 sh[SROWS * ROW_H];  // 37888 B

  const int tid  = threadIdx.x;
  const int lane = tid & 63;
  const int w    = tid >> 6;   // 0..3

  // ---- chunked XCD swizzle: adjacent slabs (same image) -> same XCD ----
  const int hwid = (int)blockIdx.x + NSLAB * (int)blockIdx.z;
  const int swz  = (hwid & 7) * CPX + (hwid >> 3);
  const int sy   = swz % NSLAB;
  const int b    = swz / NSLAB;
  const int y0   = min(sy * 12, OH - 12);   // {0,12,...,120,126}

  const int ocl = lane & 15;   // A row-offset / B col / C col (output channel)
  const int qq  = lane >> 4;

  const float* xb = x + (size_t)b * 6 * IH * IW;
  const size_t PLANE = (size_t)IH * IW;
  unsigned int* __restrict__ shu = (unsigned int*)sh;

  // ---- staging LOAD phase: 1184 items = (row:16) x (px-pair:74);
  // all 30 float2 issued before any pack ----
  float2 hv[5][6];
  #pragma unroll
  for (int it = 0; it < 5; ++it) {
    const int idx = it * 256 + tid;
    const int row = idx / 74;
    const int px2 = idx - row * 74;
    if (idx < 1184 && px2 < 71) {
      const float* pr = xb + (size_t)(y0 + row) * IW + 2 * px2;
      hv[it][0] = *(const float2*)(pr);
      hv[it][1] = *(const float2*)(pr + PLANE);
      hv[it][2] = *(const float2*)(pr + 2 * PLANE);
      hv[it][3] = *(const float2*)(pr + 3 * PLANE);
      hv[it][4] = *(const float2*)(pr + 4 * PLANE);
      hv[it][5] = *(const float2*)(pr + 5 * PLANE);
    }
  }

  // ---- B fragments + bias (independent; overlap staging latency) ----
  f16x8 Bf[5][2];
  #pragma unroll
  for (int dy = 0; dy < 5; ++dy)
    #pragma unroll
    for (int m = 0; m < 2; ++m)
      Bf[dy][m] = *(const f16x8*)(tab + ((size_t)((dy * 2 + m) * 64 + lane)) * 8);

  const float bv = (ocl < 6) ? b3[ocl] : (ocl < 15) ? b4[ocl - 6] : b6[0];

  // ---- staging PACK phase: ch 6,7 and px >= 142 -> zeros ----
  #pragma unroll
  for (int it = 0; it < 5; ++it) {
    const int idx = it * 256 + tid;
    if (idx < 1184) {
      const int row = idx / 74;
      const int px2 = idx - row * 74;
      u32x4 d0 = {0u, 0u, 0u, 0u}, d1 = {0u, 0u, 0u, 0u};
      if (px2 < 71) {
        d0[0] = pkh(hv[it][0].x, hv[it][1].x);
        d0[1] = pkh(hv[it][2].x, hv[it][3].x);
        d0[2] = pkh(hv[it][4].x, hv[it][5].x);
        d1[0] = pkh(hv[it][0].y, hv[it][1].y);
        d1[1] = pkh(hv[it][2].y, hv[it][3].y);
        d1[2] = pkh(hv[it][4].y, hv[it][5].y);
      }
      *(u32x4*)&shu[row * ROW_D + px2 * 8]     = d0;  // px even
      *(u32x4*)&shu[row * ROW_D + px2 * 8 + 4] = d1;  // px odd
    }
  }

  __syncthreads();

  // ---- 54 units = (rowpair rp:6) x (x-tile t:9), tiles fastest so the 9
  // strips of one output row store back-to-back (L2 line merge in-block) ----
  const size_t obase = ((size_t)b * 16 + ocl) * OH;
  #pragma unroll 1
  for (int i = 0; i < 14; ++i) {
    const int u = w + 4 * i;
    if (u >= 54) break;
    const int rp  = u / 9;
    const int t   = u - 9 * rp;
    const int x0t = min(t * 16, OW - 16);   // {0,16,...,112,122}
    const int voff = (x0t + ocl + qq) * 8;  // halfs; +32 for m=1 (dx+4)

    f16x8 Wp[6][2];
    #pragma unroll
    for (int k = 0; k < 6; ++k) {
      Wp[k][0] = *(const f16x8*)&sh[(2 * rp + k) * ROW_H + voff];
      Wp[k][1] = *(const f16x8*)&sh[(2 * rp + k) * ROW_H + voff + 32];
    }

    f32x4 C0 = {bv, bv, bv, bv};
    f32x4 C1 = {bv, bv, bv, bv};
    __builtin_amdgcn_s_setprio(1);
    #pragma unroll
    for (int dy = 0; dy < 5; ++dy) {
      C0 = __builtin_amdgcn_mfma_f32_16x16x32_f16(Wp[dy][0],     Bf[dy][0], C0, 0, 0, 0);
      C1 = __builtin_amdgcn_mfma_f32_16x16x32_f16(Wp[dy + 1][0], Bf[dy][0], C1, 0, 0, 0);
      C0 = __builtin_amdgcn_mfma_f32_16x16x32_f16(Wp[dy][1],     Bf[dy][1], C0, 0, 0, 0);
      C1 = __builtin_amdgcn_mfma_f32_16x16x32_f16(Wp[dy + 1][1], Bf[dy][1], C1, 0, 0, 0);
    }
    __builtin_amdgcn_s_setprio(0);

    {  // stores (nontemporal; output is write-once). Even row (y0+2rp): px base
       // = x0t + qq*4 and row*OW both ≡0 mod 4 for x0t<122 -> 16B-aligned float4.
       // Odd row (+OW, 138≡2 mod 4) and the shifted last tile stay float2.
      float* p0 = out + (obase + (y0 + 2 * rp)) * OW + x0t + qq * 4;
      float* p1 = p0 + OW;
      if (x0t != 122) {
        f32x4 s0 = {act(C0[0]), act(C0[1]), act(C0[2]), act(C0[3])};
        __builtin_nontemporal_store(s0, (f32x4*)p0);
      } else {
        f32x2 s0a = {act(C0[0]), act(C0[1])};
        f32x2 s0b = {act(C0[2]), act(C0[3])};
        __builtin_nontemporal_store(s0a, (f32x2*)p0);
        __builtin_nontemporal_store(s0b, (f32x2*)(p0 + 2));
      }
      f32x2 s1a = {act(C1[0]), act(C1[1])};
      f32x2 s1b = {act(C1[2]), act(C1[3])};
      __builtin_nontemporal_store(s1a, (f32x2*)p1);
      __builtin_nontemporal_store(s1b, (f32x2*)(p1 + 2));
    }
  }
}

extern "C" void kernel_launch(void* const* d_in, const int* in_sizes, int n_in,
                              void* d_out, int out_size, void* d_ws, size_t ws_size,
                              hipStream_t stream) {
  const float* x  = (const float*)d_in[0];
  const float* w3 = (const float*)d_in[1];
  const float* b3 = (const float*)d_in[2];
  const float* w4 = (const float*)d_in[3];
  const float* b4 = (const float*)d_in[4];
  const float* w6 = (const float*)d_in[5];
  const float* b6 = (const float*)d_in[6];
  float* out = (float*)d_out;
  _Float16* tab = (_Float16*)d_ws;  // 5120 halfs = 10 KiB

  hipLaunchKernelGGL(wprep_kernel, dim3(20), dim3(256), 0, stream, w3, w4, w6, tab);

  dim3 grid(NSLAB, 1, 256);   // y-slabs (12 rows, full width), batch
  hipLaunchKernelGGL(c3_mfma, grid, dim3(256), 0, stream, x, b3, b4, b6, tab, out);
}

// Round 19
// 152.014 us; speedup vs baseline: 1.9109x; 1.9109x over previous
//
#include <hip/hip_runtime.h>
#include <hip/hip_bf16.h>

// C3 partial connection via MFMA (fp16 in / fp32 acc), full-row-slab form.
// y = conv5x5(channel-subsets) + bias; out = 1.7159*tanh(2/3*y).
// M = 16 px, N = 16 oc, K = dx*8 + c (c pad 6->8); 2 mfma_16x16x32_f16 per
// (row, dy): m=0 dx0..3, m=1 dx4 (dx5..7 zero-weighted).
//
// R19 = R17 (best: 155us) + CACHED float4 stores on even rows only.
// R18's lesson: nontemporal bypasses L2 write-combining -> partial-sector
// stores (odd rows, row-boundary line straddles) hit HBM unmerged (WRITE
// 603MB, 290us). Cached stores are load-bearing for line merge. Even rows
// ((y0+2rp)*138 + x0t ≡ 0 mod 4 for x0t<122): one 16B store = full 64B
// sector per plane per instruction. Odd rows + last tile stay float2.
// Retained: 12-row full-width slabs, LOAD-ALL/PACK-ALL staging, tiles-
// fastest store order, chunked XCD swizzle, setprio.

#define IH 142
#define IW 142
#define OH 138
#define OW 138
#define SROWS 16
#define PXP 148                 // padded px per staged row
#define ROW_H (PXP * 8)         // 1184 halfs per row
#define ROW_D (PXP * 4)         // 592 dwords per row
#define NSLAB 12
#define NWG (NSLAB * 256)       // 3072, divisible by 8
#define CPX (NWG / 8)           // 384

typedef _Float16 f16x8 __attribute__((ext_vector_type(8)));
typedef float f32x4 __attribute__((ext_vector_type(4)));
typedef unsigned int u32x4 __attribute__((ext_vector_type(4)));

// WIDX[oc][c] = src*64 + block-index, or -1. src 0=w3(6,3,5,5) 1=w4(9,4,5,5)
// 2=w6(1,6,5,5); weight elem = blk*25 + dy*5 + dx.
__device__ __constant__ const short WIDX16[16][6] = {
  {   0,    1,    2,   -1,   -1,   -1},   // oc0  {0,1,2}
  {  -1,    3,    4,    5,   -1,   -1},   // oc1  {1,2,3}
  {  -1,   -1,    6,    7,    8,   -1},   // oc2  {2,3,4}
  {  -1,   -1,   -1,    9,   10,   11},   // oc3  {3,4,5}
  {  12,   -1,   -1,   -1,   13,   14},   // oc4  {0,4,5}
  {  15,   16,   -1,   -1,   -1,   17},   // oc5  {0,1,5}
  {64+0, 64+1, 64+2, 64+3,   -1,   -1},   // oc6  {0,1,2,3}
  {  -1, 64+4, 64+5, 64+6, 64+7,   -1},   // oc7  {1,2,3,4}
  {  -1,   -1, 64+8, 64+9, 64+10, 64+11}, // oc8  {2,3,4,5}
  {64+12,  -1,   -1, 64+13, 64+14, 64+15},// oc9  {0,3,4,5}
  {64+16, 64+17, -1,   -1, 64+18, 64+19}, // oc10 {0,1,4,5}
  {64+20, 64+21, 64+22, -1,  -1, 64+23},  // oc11 {0,1,2,5}
  {64+24, 64+25, -1, 64+26, 64+27,  -1},  // oc12 {0,1,3,4}
  {  -1, 64+28, 64+29, -1, 64+30, 64+31}, // oc13 {1,2,4,5}
  {64+32,  -1, 64+33, 64+34, -1, 64+35},  // oc14 {0,2,3,5}
  {128+0, 128+1, 128+2, 128+3, 128+4, 128+5}, // oc15 {0..5}
};

// prep: per-lane pre-swizzled B fragments, 5 dy x 2 m x 64 lanes x 8 halfs.
// k = m*32 + q*8 + j -> dx = k>>3, c = k&7; zero unless dx<5 && c<6 && consumed.
__global__ void wprep_kernel(const float* __restrict__ w3, const float* __restrict__ w4,
                             const float* __restrict__ w6, _Float16* __restrict__ tab) {
  int t = blockIdx.x * 256 + threadIdx.x;
  if (t >= 5120) return;
  int j = t & 7, lane = (t >> 3) & 63, dm = t >> 9;
  int dy = dm >> 1, m = dm & 1;
  int q = lane >> 4, oc = lane & 15;
  int k = m * 32 + q * 8 + j;
  int dx = k >> 3, c = k & 7;
  float v = 0.f;
  if (c < 6 && dx < 5) {
    int e = WIDX16[oc][c];
    if (e >= 0) {
      int src = e >> 6, blk = e & 63;
      const float* wp = (src == 0) ? w3 : (src == 1) ? w4 : w6;
      v = wp[blk * 25 + dy * 5 + dx];
    }
  }
  tab[t] = (_Float16)v;
}

__device__ __forceinline__ unsigned int pkh(float a, float b) {
  _Float16 ha = (_Float16)a, hb = (_Float16)b;
  unsigned short ua = __builtin_bit_cast(unsigned short, ha);
  unsigned short ub = __builtin_bit_cast(unsigned short, hb);
  return (unsigned int)ua | ((unsigned int)ub << 16);
}

__device__ __forceinline__ float act(float y) {
  const float TS = 1.9235933878519512f;  // 2*(2/3)*log2(e)
  const float e = __builtin_amdgcn_exp2f(y * TS);
  return fmaf(-2.f * 1.7159f, __builtin_amdgcn_rcpf(e + 1.f), 1.7159f);
}

// Block: 256 threads = 4 waves, owns rows y0..y0+11 x FULL width x 16 oc.
// Logical grid: (12 y-slabs, 256 images), XCD-chunk-swizzled.
__global__ __launch_bounds__(256, 4)
void c3_mfma(const float* __restrict__ x,
             const float* __restrict__ b3, const float* __restrict__ b4,
             const float* __restrict__ b6, const _Float16* __restrict__ tab,
             float* __restrict__ out) {
  __shared__ __attribute__((aligned(16))) _Float16 sh[SROWS * ROW_H];  // 37888 B

  const int tid  = threadIdx.x;
  const int lane = tid & 63;
  const int w    = tid >> 6;   // 0..3

  // ---- chunked XCD swizzle: adjacent slabs (same image) -> same XCD ----
  const int hwid = (int)blockIdx.x + NSLAB * (int)blockIdx.z;
  const int swz  = (hwid & 7) * CPX + (hwid >> 3);
  const int sy   = swz % NSLAB;
  const int b    = swz / NSLAB;
  const int y0   = min(sy * 12, OH - 12);   // {0,12,...,120,126}

  const int ocl = lane & 15;   // A row-offset / B col / C col (output channel)
  const int qq  = lane >> 4;

  const float* xb = x + (size_t)b * 6 * IH * IW;
  const size_t PLANE = (size_t)IH * IW;
  unsigned int* __restrict__ shu = (unsigned int*)sh;

  // ---- staging LOAD phase: 1184 items = (row:16) x (px-pair:74);
  // all 30 float2 issued before any pack ----
  float2 hv[5][6];
  #pragma unroll
  for (int it = 0; it < 5; ++it) {
    const int idx = it * 256 + tid;
    const int row = idx / 74;
    const int px2 = idx - row * 74;
    if (idx < 1184 && px2 < 71) {
      const float* pr = xb + (size_t)(y0 + row) * IW + 2 * px2;
      hv[it][0] = *(const float2*)(pr);
      hv[it][1] = *(const float2*)(pr + PLANE);
      hv[it][2] = *(const float2*)(pr + 2 * PLANE);
      hv[it][3] = *(const float2*)(pr + 3 * PLANE);
      hv[it][4] = *(const float2*)(pr + 4 * PLANE);
      hv[it][5] = *(const float2*)(pr + 5 * PLANE);
    }
  }

  // ---- B fragments + bias (independent; overlap staging latency) ----
  f16x8 Bf[5][2];
  #pragma unroll
  for (int dy = 0; dy < 5; ++dy)
    #pragma unroll
    for (int m = 0; m < 2; ++m)
      Bf[dy][m] = *(const f16x8*)(tab + ((size_t)((dy * 2 + m) * 64 + lane)) * 8);

  const float bv = (ocl < 6) ? b3[ocl] : (ocl < 15) ? b4[ocl - 6] : b6[0];

  // ---- staging PACK phase: ch 6,7 and px >= 142 -> zeros ----
  #pragma unroll
  for (int it = 0; it < 5; ++it) {
    const int idx = it * 256 + tid;
    if (idx < 1184) {
      const int row = idx / 74;
      const int px2 = idx - row * 74;
      u32x4 d0 = {0u, 0u, 0u, 0u}, d1 = {0u, 0u, 0u, 0u};
      if (px2 < 71) {
        d0[0] = pkh(hv[it][0].x, hv[it][1].x);
        d0[1] = pkh(hv[it][2].x, hv[it][3].x);
        d0[2] = pkh(hv[it][4].x, hv[it][5].x);
        d1[0] = pkh(hv[it][0].y, hv[it][1].y);
        d1[1] = pkh(hv[it][2].y, hv[it][3].y);
        d1[2] = pkh(hv[it][4].y, hv[it][5].y);
      }
      *(u32x4*)&shu[row * ROW_D + px2 * 8]     = d0;  // px even
      *(u32x4*)&shu[row * ROW_D + px2 * 8 + 4] = d1;  // px odd
    }
  }

  __syncthreads();

  // ---- 54 units = (rowpair rp:6) x (x-tile t:9), tiles fastest so the 9
  // strips of one output row store back-to-back (L2 line merge in-block) ----
  const size_t obase = ((size_t)b * 16 + ocl) * OH;
  #pragma unroll 1
  for (int i = 0; i < 14; ++i) {
    const int u = w + 4 * i;
    if (u >= 54) break;
    const int rp  = u / 9;
    const int t   = u - 9 * rp;
    const int x0t = min(t * 16, OW - 16);   // {0,16,...,112,122}
    const int voff = (x0t + ocl + qq) * 8;  // halfs; +32 for m=1 (dx+4)

    f16x8 Wp[6][2];
    #pragma unroll
    for (int k = 0; k < 6; ++k) {
      Wp[k][0] = *(const f16x8*)&sh[(2 * rp + k) * ROW_H + voff];
      Wp[k][1] = *(const f16x8*)&sh[(2 * rp + k) * ROW_H + voff + 32];
    }

    f32x4 C0 = {bv, bv, bv, bv};
    f32x4 C1 = {bv, bv, bv, bv};
    __builtin_amdgcn_s_setprio(1);
    #pragma unroll
    for (int dy = 0; dy < 5; ++dy) {
      C0 = __builtin_amdgcn_mfma_f32_16x16x32_f16(Wp[dy][0],     Bf[dy][0], C0, 0, 0, 0);
      C1 = __builtin_amdgcn_mfma_f32_16x16x32_f16(Wp[dy + 1][0], Bf[dy][0], C1, 0, 0, 0);
      C0 = __builtin_amdgcn_mfma_f32_16x16x32_f16(Wp[dy][1],     Bf[dy][1], C0, 0, 0, 0);
      C1 = __builtin_amdgcn_mfma_f32_16x16x32_f16(Wp[dy + 1][1], Bf[dy][1], C1, 0, 0, 0);
    }
    __builtin_amdgcn_s_setprio(0);

    {  // stores (CACHED - L2 write-combining is load-bearing, R18).
       // Even row: (y0+2rp)*OW + x0t + qq*4 ≡ 0 mod 4 for x0t<122 -> one
       // 16B-aligned float4 per lane (full 64B sector per plane/instr).
      float* p0 = out + (obase + (y0 + 2 * rp)) * OW + x0t + qq * 4;
      float* p1 = p0 + OW;
      if (x0t != 122) {
        *(f32x4*)p0 = (f32x4){act(C0[0]), act(C0[1]), act(C0[2]), act(C0[3])};
      } else {
        *(float2*)p0       = make_float2(act(C0[0]), act(C0[1]));
        *(float2*)(p0 + 2) = make_float2(act(C0[2]), act(C0[3]));
      }
      *(float2*)p1       = make_float2(act(C1[0]), act(C1[1]));
      *(float2*)(p1 + 2) = make_float2(act(C1[2]), act(C1[3]));
    }
  }
}

extern "C" void kernel_launch(void* const* d_in, const int* in_sizes, int n_in,
                              void* d_out, int out_size, void* d_ws, size_t ws_size,
                              hipStream_t stream) {
  const float* x  = (const float*)d_in[0];
  const float* w3 = (const float*)d_in[1];
  const float* b3 = (const float*)d_in[2];
  const float* w4 = (const float*)d_in[3];
  const float* b4 = (const float*)d_in[4];
  const float* w6 = (const float*)d_in[5];
  const float* b6 = (const float*)d_in[6];
  float* out = (float*)d_out;
  _Float16* tab = (_Float16*)d_ws;  // 5120 halfs = 10 KiB

  hipLaunchKernelGGL(wprep_kernel, dim3(20), dim3(256), 0, stream, w3, w4, w6, tab);

  dim3 grid(NSLAB, 1, 256);   // y-slabs (12 rows, full width), batch
  hipLaunchKernelGGL(c3_mfma, grid, dim3(256), 0, stream, x, b3, b4, b6, tab, out);
}